// Round 1
// baseline (12635.822 us; speedup 1.0000x reference)
//
#include <hip/hip_runtime.h>
#include <cstdint>
#include <cstddef>

#define NB 32
#define NT 64
#define NV 32000
#define NE 512
#define NH 1024
#define BOS_ID 1
#define EOS_ID 3

__device__ __forceinline__ unsigned mono_f32(float f) {
    unsigned u = __float_as_uint(f);
    return (u & 0x80000000u) ? ~u : (u | 0x80000000u);
}

// h0 = img @ Wp^T + bp ; c = 0
__global__ __launch_bounds__(256) void k_init(const float* __restrict__ img,
                                              const float* __restrict__ Wp,
                                              const float* __restrict__ bp,
                                              float* __restrict__ h0,
                                              float* __restrict__ c) {
    int g = blockIdx.x * 256 + threadIdx.x;   // 32768 outputs, one per thread
    int j = g >> 5, b = g & 31;
    const float* ir = img + (size_t)b * NH;   // D == 1024
    const float* wr = Wp + (size_t)j * NH;
    float s = bp[j];
    for (int k = 0; k < NH; k++) s = fmaf(ir[k], wr[k], s);
    h0[b * NH + j] = s;
    c[b * NH + j]  = 0.0f;
}

// logits for 128 V-columns per block + gumbel + per-block argmax partial
__global__ __launch_bounds__(256) void k_logit(const float* __restrict__ h,
                                               const float* __restrict__ Whv,
                                               const float* __restrict__ bhv,
                                               const float* __restrict__ gu,
                                               int s,
                                               unsigned long long* __restrict__ partials) {
    __shared__ float hs[32][36];    // [kk][b], stride 36: conflict-free writes, aligned f4 reads
    __shared__ float wsh[32][132];  // [kk][vv]
    __shared__ float red_s[32][32];
    __shared__ int   red_i[32][32];
    const int tid = threadIdx.x;
    const int blk = blockIdx.x;
    const int v0  = blk * 128;
    const int bq  = tid >> 5;   // 0..7  -> b tile of 4
    const int vq  = tid & 31;   // 0..31 -> v tile of 4
    float acc[4][4];
#pragma unroll
    for (int i = 0; i < 4; i++)
#pragma unroll
        for (int j = 0; j < 4; j++) acc[i][j] = 0.f;

    for (int kc = 0; kc < NH; kc += 32) {
        __syncthreads();
#pragma unroll
        for (int i = 0; i < 4; i++) {
            int idx = i * 256 + tid;
            int b = idx >> 5, kk = idx & 31;
            hs[kk][b] = h[b * NH + kc + kk];
        }
#pragma unroll
        for (int i = 0; i < 16; i++) {
            int idx = i * 256 + tid;
            int vv = idx >> 5, kk = idx & 31;
            wsh[kk][vv] = Whv[(size_t)(v0 + vv) * NH + kc + kk];
        }
        __syncthreads();
#pragma unroll
        for (int kk = 0; kk < 32; kk++) {
            float4 hv4 = *(const float4*)&hs[kk][bq * 4];
            float4 wv4 = *(const float4*)&wsh[kk][vq * 4];
            float hv[4] = {hv4.x, hv4.y, hv4.z, hv4.w};
            float wv[4] = {wv4.x, wv4.y, wv4.z, wv4.w};
#pragma unroll
            for (int bi = 0; bi < 4; bi++)
#pragma unroll
                for (int vi = 0; vi < 4; vi++)
                    acc[bi][vi] = fmaf(hv[bi], wv[vi], acc[bi][vi]);
        }
    }

    // epilogue: + b_hv + gumbel, local argmax (lowest index on ties)
    const float4 bv4 = *(const float4*)&bhv[v0 + vq * 4];
    float bvv[4] = {bv4.x, bv4.y, bv4.z, bv4.w};
#pragma unroll
    for (int bi = 0; bi < 4; bi++) {
        int b = bq * 4 + bi;
        const float4 uv4 = *(const float4*)&gu[((size_t)s * NB + b) * NV + v0 + vq * 4];
        float uvv[4] = {uv4.x, uv4.y, uv4.z, uv4.w};
        float best = -3.4e38f;
        int bidx = v0 + vq * 4;
#pragma unroll
        for (int vi = 0; vi < 4; vi++) {
            float g  = -logf(-logf(uvv[vi] + 1e-10f) + 1e-10f);
            float sc = acc[bi][vi] + bvv[vi] + g;   // TAU == 1.0
            if (sc > best) { best = sc; bidx = v0 + vq * 4 + vi; }
        }
        red_s[b][vq] = best;
        red_i[b][vq] = bidx;
    }
    __syncthreads();
    if (tid < 32) {
        int b = tid;
        float bs = red_s[b][0];
        int   bi = red_i[b][0];
        for (int q = 1; q < 32; q++) {
            float v = red_s[b][q];
            if (v > bs) { bs = v; bi = red_i[b][q]; }
        }
        unsigned long long key =
            ((unsigned long long)mono_f32(bs) << 32) | (unsigned)(~(unsigned)bi);
        partials[blk * 32 + b] = key;
    }
}

// redundant argmax-finalize + LSTM cell slice (4 h-outputs per block)
__global__ __launch_bounds__(256) void k_lstm(const float* __restrict__ h,
                                              float* __restrict__ hn,
                                              float* __restrict__ cbuf,
                                              const float* __restrict__ emb,
                                              const float* __restrict__ Wih,
                                              const float* __restrict__ Whh,
                                              const float* __restrict__ bih,
                                              const float* __restrict__ bhh,
                                              const unsigned long long* __restrict__ partials,
                                              int* __restrict__ hist,
                                              int s, int skip) {
    __shared__ float Wt[512][20];   // [k][slot], stride 20: aligned f4, conflict-free reads
    __shared__ float xh[32][517];   // [b][k], stride 517: odd*? -> spread banks
    __shared__ int labels[32];
    const int tid = threadIdx.x, blk = blockIdx.x;
    const int b8 = tid >> 3, ks = tid & 7;

    if (s < 0) {
        if (tid < 32) labels[tid] = BOS_ID;
    } else {
        unsigned long long best = 0ull;
        for (int p = ks; p < 250; p += 8) {
            unsigned long long k = partials[p * 32 + b8];
            if (k > best) best = k;
        }
#pragma unroll
        for (int m = 1; m < 8; m <<= 1) {
            unsigned long long o = (unsigned long long)__shfl_xor((long long)best, m, 64);
            if (o > best) best = o;
        }
        if (ks == 0) labels[b8] = (int)(~(unsigned)best);
    }
    __syncthreads();
    if (s >= 0 && blk == 0 && tid < 32) hist[s * 32 + tid] = labels[tid];
    if (skip) return;

    const int j0 = blk * 4;
    float acc[16];
#pragma unroll
    for (int r = 0; r < 16; r++) acc[r] = 0.f;

    for (int chunk = 0; chunk < 3; chunk++) {
        __syncthreads();
#pragma unroll
        for (int i = 0; i < 32; i++) {     // stage 16 gate rows x 512 k
            int idx = i * 256 + tid;
            int slot = idx >> 9, k = idx & 511;
            int gate = slot >> 2, jj = slot & 3;
            int row = gate * NH + j0 + jj;
            float w = (chunk == 0) ? Wih[(size_t)row * NE + k]
                                   : Whh[(size_t)row * NH + (chunk - 1) * 512 + k];
            Wt[k][slot] = w;
        }
#pragma unroll
        for (int i = 0; i < 64; i++) {     // stage x / h chunk
            int idx = i * 256 + tid;
            int b = idx >> 9, k = idx & 511;
            float xv = (chunk == 0) ? emb[(size_t)labels[b] * NE + k]
                                    : h[b * NH + (chunk - 1) * 512 + k];
            xh[b][k] = xv;
        }
        __syncthreads();
#pragma unroll 4
        for (int i = 0; i < 64; i++) {
            int k = ks + 8 * i;
            float xv = xh[b8][k];
            const float4 w0 = *(const float4*)&Wt[k][0];
            const float4 w1 = *(const float4*)&Wt[k][4];
            const float4 w2 = *(const float4*)&Wt[k][8];
            const float4 w3 = *(const float4*)&Wt[k][12];
            acc[0]  = fmaf(xv, w0.x, acc[0]);  acc[1]  = fmaf(xv, w0.y, acc[1]);
            acc[2]  = fmaf(xv, w0.z, acc[2]);  acc[3]  = fmaf(xv, w0.w, acc[3]);
            acc[4]  = fmaf(xv, w1.x, acc[4]);  acc[5]  = fmaf(xv, w1.y, acc[5]);
            acc[6]  = fmaf(xv, w1.z, acc[6]);  acc[7]  = fmaf(xv, w1.w, acc[7]);
            acc[8]  = fmaf(xv, w2.x, acc[8]);  acc[9]  = fmaf(xv, w2.y, acc[9]);
            acc[10] = fmaf(xv, w2.z, acc[10]); acc[11] = fmaf(xv, w2.w, acc[11]);
            acc[12] = fmaf(xv, w3.x, acc[12]); acc[13] = fmaf(xv, w3.y, acc[13]);
            acc[14] = fmaf(xv, w3.z, acc[14]); acc[15] = fmaf(xv, w3.w, acc[15]);
        }
    }
#pragma unroll
    for (int m = 1; m < 8; m <<= 1)
#pragma unroll
        for (int r = 0; r < 16; r++) acc[r] += __shfl_xor(acc[r], m, 64);

    if (ks == 0) {
        int b = b8;
#pragma unroll
        for (int jj = 0; jj < 4; jj++) {
            int j = j0 + jj;
            float gi = acc[0 + jj]  + bih[j]          + bhh[j];
            float gf = acc[4 + jj]  + bih[NH + j]     + bhh[NH + j];
            float gg = acc[8 + jj]  + bih[2 * NH + j] + bhh[2 * NH + j];
            float go = acc[12 + jj] + bih[3 * NH + j] + bhh[3 * NH + j];
            float si = 1.f / (1.f + expf(-gi));
            float sf = 1.f / (1.f + expf(-gf));
            float so = 1.f / (1.f + expf(-go));
            float cn = sf * cbuf[b * NH + j] + si * tanhf(gg);
            float hv = so * tanhf(cn);
            cbuf[b * NH + j] = cn;
            hn[b * NH + j]   = hv;
        }
    }
}

// ids / lengths from label history
__global__ __launch_bounds__(64) void k_out(const int* __restrict__ hist,
                                            float* __restrict__ out) {
    int b = threadIdx.x;
    if (b >= 32) return;
    int te = 63;   // first EOS index (t=63 forced EOS)
    for (int t = 0; t < 63; t++)
        if (hist[t * 32 + b] == EOS_ID) { te = t; break; }
    for (int t = 0; t < 64; t++) {
        int lab = (t < 63) ? hist[t * 32 + b] : EOS_ID;
        int id = (t < te) ? lab : 0;           // pad_g true strictly before first EOS
        out[b * 64 + t] = (float)id;
    }
    out[2048 + (size_t)NB * NT * NV + b] = (float)(te + 1);
}

// zero logits region + scatter one-hot (message_logits == one_hot(message_ids))
__global__ __launch_bounds__(256) void k_scatter(float* __restrict__ out) {
    const int bt = blockIdx.x;                 // b*64 + t
    float* row = out + 2048 + (size_t)bt * NV;
    const int id = (int)out[bt];               // ids already written by k_out
    float4 z = make_float4(0.f, 0.f, 0.f, 0.f);
    for (int i = threadIdx.x; i < NV / 4; i += 256) ((float4*)row)[i] = z;
    __syncthreads();
    if (threadIdx.x == 0) row[id] = 1.0f;
}

extern "C" void kernel_launch(void* const* d_in, const int* in_sizes, int n_in,
                              void* d_out, int out_size, void* d_ws, size_t ws_size,
                              hipStream_t stream) {
    const float* img = (const float*)d_in[0];
    const float* gu  = (const float*)d_in[1];
    const float* Wp  = (const float*)d_in[2];
    const float* bp  = (const float*)d_in[3];
    const float* emb = (const float*)d_in[4];
    const float* Wih = (const float*)d_in[5];
    const float* Whh = (const float*)d_in[6];
    const float* bih = (const float*)d_in[7];
    const float* bhh = (const float*)d_in[8];
    const float* Whv = (const float*)d_in[9];
    const float* bhv = (const float*)d_in[10];
    float* out = (float*)d_out;

    // scratch lives inside the logits region of d_out (fully overwritten by k_scatter)
    float* scratch = out + 2048;
    float* hA = scratch;                 // 32768
    float* hB = scratch + 32768;         // 32768
    float* cb = scratch + 65536;         // 32768
    unsigned long long* partials = (unsigned long long*)(scratch + 98304); // 8000 u64
    int* hist = (int*)(scratch + 98304 + 16000);                           // 63*32 ints

    k_init<<<128, 256, 0, stream>>>(img, Wp, bp, hB, cb);
    // initial LSTM cell with x0 = emb[BOS], h = h0, c = 0  -> writes hA
    k_lstm<<<256, 256, 0, stream>>>(hB, hA, cb, emb, Wih, Whh, bih, bhh,
                                    (const unsigned long long*)nullptr, hist, -1, 0);
    for (int s = 0; s < 63; s++) {
        const float* hc = (s & 1) ? hB : hA;
        float* hn       = (s & 1) ? hA : hB;
        k_logit<<<250, 256, 0, stream>>>(hc, Whv, bhv, gu, s, partials);
        k_lstm<<<256, 256, 0, stream>>>(hc, hn, cb, emb, Wih, Whh, bih, bhh,
                                        partials, hist, s, (s == 62) ? 1 : 0);
    }
    k_out<<<1, 64, 0, stream>>>(hist, out);
    k_scatter<<<2048, 256, 0, stream>>>(out);
}

// Round 2
// 12431.912 us; speedup vs baseline: 1.0164x; 1.0164x over previous
//
#include <hip/hip_runtime.h>
#include <cstdint>
#include <cstddef>

#define NB 32
#define NT 64
#define NV 32000
#define NE 512
#define NH 1024
#define BOS_ID 1
#define EOS_ID 3
#define KC 64

__device__ __forceinline__ unsigned mono_f32(float f) {
    unsigned u = __float_as_uint(f);
    return (u & 0x80000000u) ? ~u : (u | 0x80000000u);
}

// h0 = img @ Wp^T + bp ; c = 0
__global__ __launch_bounds__(256) void k_init(const float* __restrict__ img,
                                              const float* __restrict__ Wp,
                                              const float* __restrict__ bp,
                                              float* __restrict__ h0,
                                              float* __restrict__ c) {
    int g = blockIdx.x * 256 + threadIdx.x;   // 32768 outputs, one per thread
    int j = g >> 5, b = g & 31;
    const float* ir = img + (size_t)b * NH;   // D == 1024
    const float* wr = Wp + (size_t)j * NH;
    float s = bp[j];
    for (int k = 0; k < NH; k++) s = fmaf(ir[k], wr[k], s);
    h0[b * NH + j] = s;
    c[b * NH + j]  = 0.0f;
}

// logits + gumbel + argmax partial via device atomicMax.
// 250 blocks x 512 threads; 128 v-cols/block; double-buffered K-chunks of 64.
// Per-thread tile: 2 b x 4 v. k accumulation order identical to round-1 kernel.
__global__ __launch_bounds__(512) void k_logit(const float* __restrict__ h,
                                               const float* __restrict__ Whv,
                                               const float* __restrict__ bhv,
                                               const float* __restrict__ gu,
                                               int s,
                                               unsigned long long* __restrict__ slot) {
    __shared__ float wsh[2][KC][132];   // [buf][k][v] stride 132: aligned b128 reads
    __shared__ float hs[2][KC][34];     // [buf][k][b] stride 34: aligned b64 reads
    const int tid = threadIdx.x;
    const int v0  = blockIdx.x * 128;
    const int vq  = tid & 31;           // v-group of 4 (contiguous)
    const int bq  = tid >> 5;           // 0..15 -> b pair
    const int wq  = tid & 15;           // staging: k-quad within chunk (k = wq*4+j)
    const int wv  = tid >> 4;           // staging: 0..31

    float4 wr[4];
    float4 hr;
    float acc[2][4];
#pragma unroll
    for (int bi = 0; bi < 2; bi++)
#pragma unroll
        for (int j = 0; j < 4; j++) acc[bi][j] = 0.f;

    auto load_chunk = [&](int kc) {
#pragma unroll
        for (int i = 0; i < 4; i++) {
            int vv = i * 32 + wv;
            wr[i] = *(const float4*)&Whv[(size_t)(v0 + vv) * NH + kc + wq * 4];
        }
        hr = *(const float4*)&h[wv * NH + kc + wq * 4];   // wv==b for h staging
    };
    auto store_chunk = [&](int p) {
#pragma unroll
        for (int i = 0; i < 4; i++) {
            int vv = i * 32 + wv;
            wsh[p][wq * 4 + 0][vv] = wr[i].x;
            wsh[p][wq * 4 + 1][vv] = wr[i].y;
            wsh[p][wq * 4 + 2][vv] = wr[i].z;
            wsh[p][wq * 4 + 3][vv] = wr[i].w;
        }
        hs[p][wq * 4 + 0][wv] = hr.x;
        hs[p][wq * 4 + 1][wv] = hr.y;
        hs[p][wq * 4 + 2][wv] = hr.z;
        hs[p][wq * 4 + 3][wv] = hr.w;
    };

    load_chunk(0);
    store_chunk(0);
    load_chunk(KC);                      // chunk 1 -> regs (in flight / held)

    const int NCH = NH / KC;             // 16
    for (int c = 0; c < NCH; c++) {
        __syncthreads();                 // LDS[c&1] ready for all waves
        const int p = c & 1;
#pragma unroll 16
        for (int kk = 0; kk < KC; kk++) {
            float4 wv4 = *(const float4*)&wsh[p][kk][vq * 4];
            float2 hv2 = *(const float2*)&hs[p][kk][bq * 2];
            acc[0][0] = fmaf(hv2.x, wv4.x, acc[0][0]);
            acc[0][1] = fmaf(hv2.x, wv4.y, acc[0][1]);
            acc[0][2] = fmaf(hv2.x, wv4.z, acc[0][2]);
            acc[0][3] = fmaf(hv2.x, wv4.w, acc[0][3]);
            acc[1][0] = fmaf(hv2.y, wv4.x, acc[1][0]);
            acc[1][1] = fmaf(hv2.y, wv4.y, acc[1][1]);
            acc[1][2] = fmaf(hv2.y, wv4.z, acc[1][2]);
            acc[1][3] = fmaf(hv2.y, wv4.w, acc[1][3]);
        }
        if (c + 1 < NCH) {
            store_chunk(1 - p);                       // waits vmcnt for regs
            if (c + 2 < NCH) load_chunk((c + 2) * KC);
        }
    }

    // epilogue: + b_hv + gumbel, argmax (lowest index on ties)
    const float4 bv4 = *(const float4*)&bhv[v0 + vq * 4];
    float bvv[4] = {bv4.x, bv4.y, bv4.z, bv4.w};
    unsigned long long key[2];
#pragma unroll
    for (int bi = 0; bi < 2; bi++) {
        int b = bq * 2 + bi;
        const float4 u4 = *(const float4*)&gu[((size_t)s * NB + b) * NV + v0 + vq * 4];
        float uvv[4] = {u4.x, u4.y, u4.z, u4.w};
        float best = -3.4e38f;
        int bidx = v0 + vq * 4;
#pragma unroll
        for (int j = 0; j < 4; j++) {
            float g  = -logf(-logf(uvv[j] + 1e-10f) + 1e-10f);
            float sc = acc[bi][j] + bvv[j] + g;      // TAU == 1.0
            if (sc > best) { best = sc; bidx = v0 + vq * 4 + j; }
        }
        key[bi] = ((unsigned long long)mono_f32(best) << 32) | (unsigned)(~(unsigned)bidx);
    }
#pragma unroll
    for (int m = 1; m < 32; m <<= 1) {
#pragma unroll
        for (int bi = 0; bi < 2; bi++) {
            unsigned long long o =
                (unsigned long long)__shfl_xor((long long)key[bi], m, 32);
            if (o > key[bi]) key[bi] = o;
        }
    }
    if (vq == 0) {
#pragma unroll
        for (int bi = 0; bi < 2; bi++)
            atomicMax(&slot[(s & 1) * 32 + bq * 2 + bi], key[bi]);
    }
}

// argmax-finalize (read slots) + LSTM cell slice (4 h-outputs per block)
__global__ __launch_bounds__(256) void k_lstm(const float* __restrict__ h,
                                              float* __restrict__ hn,
                                              float* __restrict__ cbuf,
                                              const float* __restrict__ emb,
                                              const float* __restrict__ Wih,
                                              const float* __restrict__ Whh,
                                              const float* __restrict__ bih,
                                              const float* __restrict__ bhh,
                                              unsigned long long* __restrict__ slot,
                                              int* __restrict__ hist,
                                              int s, int skip) {
    __shared__ float Wt[512][20];   // [k][slot], stride 20: aligned f4, conflict-free reads
    __shared__ float xh[32][517];   // [b][k], stride 517: 2-way max on reads
    __shared__ int labels[32];
    const int tid = threadIdx.x, blk = blockIdx.x;
    const int b8 = tid >> 3, ks = tid & 7;

    if (s < 0) {
        if (tid < 32) labels[tid] = BOS_ID;
    } else {
        if (tid < 32) labels[tid] = (int)(~(unsigned)slot[(s & 1) * 32 + tid]);
    }
    if (tid >= 32 && tid < 64)
        slot[((s + 1) & 1) * 32 + (tid - 32)] = 0ull;   // pre-zero next parity
    if (s >= 0 && blk == 0 && tid < 32) hist[s * 32 + tid] = labels[tid];
    if (skip) return;

    const int j0 = blk * 4;
    float acc[16];
#pragma unroll
    for (int r = 0; r < 16; r++) acc[r] = 0.f;

    for (int chunk = 0; chunk < 3; chunk++) {
        __syncthreads();
#pragma unroll
        for (int i = 0; i < 32; i++) {     // stage 16 gate rows x 512 k
            int idx = i * 256 + tid;
            int slot_i = idx >> 9, k = idx & 511;
            int gate = slot_i >> 2, jj = slot_i & 3;
            int row = gate * NH + j0 + jj;
            float w = (chunk == 0) ? Wih[(size_t)row * NE + k]
                                   : Whh[(size_t)row * NH + (chunk - 1) * 512 + k];
            Wt[k][slot_i] = w;
        }
#pragma unroll
        for (int i = 0; i < 64; i++) {     // stage x / h chunk
            int idx = i * 256 + tid;
            int b = idx >> 9, k = idx & 511;
            float xv = (chunk == 0) ? emb[(size_t)labels[b] * NE + k]
                                    : h[b * NH + (chunk - 1) * 512 + k];
            xh[b][k] = xv;
        }
        __syncthreads();
#pragma unroll 4
        for (int i = 0; i < 64; i++) {
            int k = ks + 8 * i;
            float xv = xh[b8][k];
            const float4 w0 = *(const float4*)&Wt[k][0];
            const float4 w1 = *(const float4*)&Wt[k][4];
            const float4 w2 = *(const float4*)&Wt[k][8];
            const float4 w3 = *(const float4*)&Wt[k][12];
            acc[0]  = fmaf(xv, w0.x, acc[0]);  acc[1]  = fmaf(xv, w0.y, acc[1]);
            acc[2]  = fmaf(xv, w0.z, acc[2]);  acc[3]  = fmaf(xv, w0.w, acc[3]);
            acc[4]  = fmaf(xv, w1.x, acc[4]);  acc[5]  = fmaf(xv, w1.y, acc[5]);
            acc[6]  = fmaf(xv, w1.z, acc[6]);  acc[7]  = fmaf(xv, w1.w, acc[7]);
            acc[8]  = fmaf(xv, w2.x, acc[8]);  acc[9]  = fmaf(xv, w2.y, acc[9]);
            acc[10] = fmaf(xv, w2.z, acc[10]); acc[11] = fmaf(xv, w2.w, acc[11]);
            acc[12] = fmaf(xv, w3.x, acc[12]); acc[13] = fmaf(xv, w3.y, acc[13]);
            acc[14] = fmaf(xv, w3.z, acc[14]); acc[15] = fmaf(xv, w3.w, acc[15]);
        }
    }
#pragma unroll
    for (int m = 1; m < 8; m <<= 1)
#pragma unroll
        for (int r = 0; r < 16; r++) acc[r] += __shfl_xor(acc[r], m, 64);

    if (ks == 0) {
        int b = b8;
#pragma unroll
        for (int jj = 0; jj < 4; jj++) {
            int j = j0 + jj;
            float gi = acc[0 + jj]  + bih[j]          + bhh[j];
            float gf = acc[4 + jj]  + bih[NH + j]     + bhh[NH + j];
            float gg = acc[8 + jj]  + bih[2 * NH + j] + bhh[2 * NH + j];
            float go = acc[12 + jj] + bih[3 * NH + j] + bhh[3 * NH + j];
            float si = 1.f / (1.f + expf(-gi));
            float sf = 1.f / (1.f + expf(-gf));
            float so = 1.f / (1.f + expf(-go));
            float cn = sf * cbuf[b * NH + j] + si * tanhf(gg);
            float hv = so * tanhf(cn);
            cbuf[b * NH + j] = cn;
            hn[b * NH + j]   = hv;
        }
    }
}

// ids / lengths from label history
__global__ __launch_bounds__(64) void k_out(const int* __restrict__ hist,
                                            float* __restrict__ out) {
    int b = threadIdx.x;
    if (b >= 32) return;
    int te = 63;   // first EOS index (t=63 forced EOS)
    for (int t = 0; t < 63; t++)
        if (hist[t * 32 + b] == EOS_ID) { te = t; break; }
    for (int t = 0; t < 64; t++) {
        int lab = (t < 63) ? hist[t * 32 + b] : EOS_ID;
        int id = (t < te) ? lab : 0;           // pad_g true strictly before first EOS
        out[b * 64 + t] = (float)id;
    }
    out[2048 + (size_t)NB * NT * NV + b] = (float)(te + 1);
}

// zero logits region + scatter one-hot (message_logits == one_hot(message_ids))
__global__ __launch_bounds__(256) void k_scatter(float* __restrict__ out) {
    const int bt = blockIdx.x;                 // b*64 + t
    float* row = out + 2048 + (size_t)bt * NV;
    const int id = (int)out[bt];               // ids already written by k_out
    float4 z = make_float4(0.f, 0.f, 0.f, 0.f);
    for (int i = threadIdx.x; i < NV / 4; i += 256) ((float4*)row)[i] = z;
    __syncthreads();
    if (threadIdx.x == 0) row[id] = 1.0f;
}

extern "C" void kernel_launch(void* const* d_in, const int* in_sizes, int n_in,
                              void* d_out, int out_size, void* d_ws, size_t ws_size,
                              hipStream_t stream) {
    const float* img = (const float*)d_in[0];
    const float* gu  = (const float*)d_in[1];
    const float* Wp  = (const float*)d_in[2];
    const float* bp  = (const float*)d_in[3];
    const float* emb = (const float*)d_in[4];
    const float* Wih = (const float*)d_in[5];
    const float* Whh = (const float*)d_in[6];
    const float* bih = (const float*)d_in[7];
    const float* bhh = (const float*)d_in[8];
    const float* Whv = (const float*)d_in[9];
    const float* bhv = (const float*)d_in[10];
    float* out = (float*)d_out;

    // scratch lives inside the logits region of d_out (fully overwritten by k_scatter)
    float* scratch = out + 2048;
    float* hA = scratch;                 // 32768
    float* hB = scratch + 32768;         // 32768
    float* cb = scratch + 65536;         // 32768
    unsigned long long* slot = (unsigned long long*)(scratch + 98304); // 64 u64 (2 parities)
    int* hist = (int*)(scratch + 98304 + 128);                         // 63*32 ints

    k_init<<<128, 256, 0, stream>>>(img, Wp, bp, hB, cb);
    // initial LSTM cell with x0 = emb[BOS], h = h0, c = 0 -> writes hA; zeroes slot parity 0
    k_lstm<<<256, 256, 0, stream>>>(hB, hA, cb, emb, Wih, Whh, bih, bhh,
                                    slot, hist, -1, 0);
    for (int s = 0; s < 63; s++) {
        const float* hc = (s & 1) ? hB : hA;
        float* hn       = (s & 1) ? hA : hB;
        k_logit<<<250, 512, 0, stream>>>(hc, Whv, bhv, gu, s, slot);
        k_lstm<<<256, 256, 0, stream>>>(hc, hn, cb, emb, Wih, Whh, bih, bhh,
                                        slot, hist, s, (s == 62) ? 1 : 0);
    }
    k_out<<<1, 64, 0, stream>>>(hist, out);
    k_scatter<<<2048, 256, 0, stream>>>(out);
}